// Round 12
// baseline (1137.223 us; speedup 1.0000x reference)
//
#include <hip/hip_runtime.h>
#include <cstdint>

#define LOG2E 1.4426950408889634f
#define BCH 16                 // batches per chunk
#define RC  (BCH * 2048)       // rows per chunk = 32768

typedef __attribute__((ext_vector_type(8))) short short8;
typedef __attribute__((ext_vector_type(4))) float f32x4;
typedef __attribute__((ext_vector_type(4))) unsigned short ush4;
typedef __attribute__((ext_vector_type(8))) unsigned short ush8;

__device__ __forceinline__ float b2f(unsigned short u) {
  union { unsigned int u; float f; } c; c.u = ((unsigned int)u) << 16; return c.f;
}
__device__ __forceinline__ unsigned short f2b(float f) {
  union { float f; unsigned int u; } c; c.f = f;
  unsigned int r = c.u + 0x7FFFu + ((c.u >> 16) & 1u);
  return (unsigned short)(r >> 16);
}
// HW exp2 (exp2f goes through OCML). r4: poly exp2 regressed. r5/r6: packed
// fp32 dead. r7/r8: residency pinned ~16 waves/CU regardless of config.
// r9: XD LDS staging neutral -> XD access exonerated. r10/r11: broker infra
// failures (pre-kernel). This round: two independent recurrences per wave
// (ILP) — the one untried per-wave-stall lever.
__device__ __forceinline__ float ex2(float x) { return __builtin_amdgcn_exp2f(x); }
__device__ __forceinline__ f32x4 exp2v(f32x4 v) {
  f32x4 r; r.x = ex2(v.x); r.y = ex2(v.y); r.z = ex2(v.z); r.w = ex2(v.w);
  return r;
}

// opaque 16B load: result cannot be rematerialized -> stays in VGPRs
__device__ __forceinline__ f32x4 ld4(const float* p) {
  f32x4 r;
  asm volatile("global_load_dwordx4 %0, %1, off" : "=v"(r) : "v"(p));
  return r;
}

// async global->LDS, 16B/lane; LDS dest contiguous in lane order (base+lane*16B)
__device__ __forceinline__ void gl2lds16(void* l, const void* g) {
  __builtin_amdgcn_global_load_lds(
      (const __attribute__((address_space(1))) void*)g,
      (__attribute__((address_space(3))) void*)l, 16, 0, 0);
}

// ---------------- weight prep: fp32 -> bf16, and AA = -exp(A_log)*log2e ----
__global__ __launch_bounds__(256) void prep_weights(
    const float* __restrict__ inw, const float* __restrict__ xw,
    const float* __restrict__ ow, const float* __restrict__ alog,
    unsigned short* __restrict__ inwb, unsigned short* __restrict__ xwb,
    unsigned short* __restrict__ owb, float* __restrict__ AA) {
  int gid = blockIdx.x * 256 + threadIdx.x;
  const int n_in = 2 * 1024 * 256;   // 524288
  const int n_x  = 2 * 48 * 512;     // 49152
  const int n_o  = 2 * 256 * 512;    // 262144
  const int n_a  = 2 * 512 * 16;     // 16384
  if (gid < n_in) { inwb[gid] = f2b(inw[gid]); return; }
  gid -= n_in;
  if (gid < n_x) { xwb[gid] = f2b(xw[gid]); return; }
  gid -= n_x;
  if (gid < n_o) { owb[gid] = f2b(ow[gid]); return; }
  gid -= n_o;
  if (gid < n_a) { AA[gid] = -__expf(alog[gid]) * LOG2E; }
}

// ---------------- LayerNorm: one wave per row, X fp32 -> XN bf16 -----------
__global__ __launch_bounds__(256) void ln_fwd(
    const float* __restrict__ X, const float* __restrict__ w,
    const float* __restrict__ b, unsigned short* __restrict__ XN) {
  int wv = threadIdx.x >> 6, ln = threadIdx.x & 63;
  long row = (long)blockIdx.x * 4 + wv;
  f32x4 v = ((const f32x4*)(X + row * 256))[ln];
  float s = v.x + v.y + v.z + v.w;
  float s2 = v.x * v.x + v.y * v.y + v.z * v.z + v.w * v.w;
  #pragma unroll
  for (int o = 32; o > 0; o >>= 1) {
    s += __shfl_xor(s, o, 64);
    s2 += __shfl_xor(s2, o, 64);
  }
  float mu = s * (1.f / 256.f);
  float var = s2 * (1.f / 256.f) - mu * mu;
  float rst = rsqrtf(var + 1e-5f);
  f32x4 wv4 = ((const f32x4*)w)[ln];
  f32x4 bv4 = ((const f32x4*)b)[ln];
  ush4 o4;
  o4.x = f2b((v.x - mu) * rst * wv4.x + bv4.x);
  o4.y = f2b((v.y - mu) * rst * wv4.y + bv4.y);
  o4.z = f2b((v.z - mu) * rst * wv4.z + bv4.z);
  o4.w = f2b((v.w - mu) * rst * wv4.w + bv4.w);
  ((ush4*)(XN + row * 256))[ln] = o4;
}

// ---------------- layer-0 LN: mask + write masked residual X + LN ----------
// Replaces the standalone mask_x pass (268 MB of traffic): reads raw x,
// zeroes masked rows (wave-uniform), writes the masked X (residual base for
// gemm64) and the LN output in one sweep.
__global__ __launch_bounds__(256) void ln_mask_fwd(
    const float* __restrict__ Xin, const int* __restrict__ mask,
    const float* __restrict__ w, const float* __restrict__ b,
    float* __restrict__ Xout, unsigned short* __restrict__ XN) {
  int wv = threadIdx.x >> 6, ln = threadIdx.x & 63;
  long row = (long)blockIdx.x * 4 + wv;
  f32x4 v = ((const f32x4*)(Xin + row * 256))[ln];
  if (!mask[row]) { v.x = 0.f; v.y = 0.f; v.z = 0.f; v.w = 0.f; }
  ((f32x4*)(Xout + row * 256))[ln] = v;
  float s = v.x + v.y + v.z + v.w;
  float s2 = v.x * v.x + v.y * v.y + v.z * v.z + v.w * v.w;
  #pragma unroll
  for (int o = 32; o > 0; o >>= 1) {
    s += __shfl_xor(s, o, 64);
    s2 += __shfl_xor(s2, o, 64);
  }
  float mu = s * (1.f / 256.f);
  float var = s2 * (1.f / 256.f) - mu * mu;
  float rst = rsqrtf(var + 1e-5f);
  f32x4 wv4 = ((const f32x4*)w)[ln];
  f32x4 bv4 = ((const f32x4*)b)[ln];
  ush4 o4;
  o4.x = f2b((v.x - mu) * rst * wv4.x + bv4.x);
  o4.y = f2b((v.y - mu) * rst * wv4.y + bv4.y);
  o4.z = f2b((v.z - mu) * rst * wv4.z + bv4.z);
  o4.w = f2b((v.w - mu) * rst * wv4.w + bv4.w);
  ((ush4*)(XN + row * 256))[ln] = o4;
}

// ---------------- 128x128 bf16 MFMA GEMM, C = A(MxK) * B(NxK)^T ------------
// split store bf16: col<512 -> OutU, else OutZ (for in_proj)
// XCD-chunked block swizzle: the 8 sharers of an A panel co-resident on 1 XCD.
__global__ __launch_bounds__(256) void gemm128(
    const unsigned short* __restrict__ A, const unsigned short* __restrict__ B,
    unsigned short* __restrict__ OutU, unsigned short* __restrict__ OutZ,
    int N, int K) {
  __shared__ unsigned short As[128 * 32];
  __shared__ unsigned short Bs[128 * 32];
  const int tid = threadIdx.x;
  const int wave = tid >> 6, lane = tid & 63;
  const int lin = blockIdx.x + blockIdx.y * 256;   // dispatch order, 0..2047
  const int xcd = lin & 7, idx = lin >> 3;
  const int m0 = (xcd * 32 + (idx >> 3)) * 128;    // 256 row-blocks
  const int n0 = (idx & 7) * 128;                  // 8 col-blocks
  const int wm = (wave >> 1) * 64, wn = (wave & 1) * 64;

  f32x4 acc[4][4];
  #pragma unroll
  for (int i = 0; i < 4; i++)
    #pragma unroll
    for (int j = 0; j < 4; j++)
      #pragma unroll
      for (int r = 0; r < 4; r++) acc[i][j][r] = 0.f;

  const int srow = wave * 32 + (lane >> 2);
  const int skcol = (lane & 3) * 8;
  unsigned short* AsW = &As[srow * 32 + skcol];
  unsigned short* BsW = &Bs[srow * 32 + skcol];
  const unsigned short* Ag = A + (long)(m0 + srow) * K + skcol;
  const unsigned short* Bg = B + (long)(n0 + srow) * K + skcol;

  const int fr = lane & 15, fk = (lane >> 4) * 8;

  for (int k0 = 0; k0 < K; k0 += 32) {
    gl2lds16(AsW,            Ag + k0);
    gl2lds16(AsW + 16 * 32,  Ag + (long)16 * K + k0);
    gl2lds16(BsW,            Bg + k0);
    gl2lds16(BsW + 16 * 32,  Bg + (long)16 * K + k0);
    __syncthreads();
    short8 af[4], bf[4];
    #pragma unroll
    for (int i = 0; i < 4; i++) {
      af[i] = *(const short8*)&As[(wm + i * 16 + fr) * 32 + fk];
      bf[i] = *(const short8*)&Bs[(wn + i * 16 + fr) * 32 + fk];
    }
    #pragma unroll
    for (int i = 0; i < 4; i++)
      #pragma unroll
      for (int j = 0; j < 4; j++)
        acc[i][j] = __builtin_amdgcn_mfma_f32_16x16x32_bf16(af[i], bf[j], acc[i][j], 0, 0, 0);
    __syncthreads();
  }

  const int cl = lane & 15, rq = (lane >> 4) * 4;
  #pragma unroll
  for (int i = 0; i < 4; i++)
    #pragma unroll
    for (int j = 0; j < 4; j++) {
      int col = n0 + wn + j * 16 + cl;
      #pragma unroll
      for (int r = 0; r < 4; r++) {
        int row = m0 + wm + i * 16 + rq + r;
        float v = acc[i][j][r];
        if (col < 512) OutU[(long)row * 512 + col] = f2b(v);
        else           OutZ[(long)row * 512 + (col - 512)] = f2b(v);
      }
    }
}

// ---------------- 64x128 bf16 MFMA GEMM for out_proj (more blocks/CU) ------
// OutF[row*N+col] = Xres[row*N+col] + (mask[row] ? acc : 0)
__global__ __launch_bounds__(256) void gemm64(
    const unsigned short* __restrict__ A, const unsigned short* __restrict__ B,
    const float* __restrict__ Xres, float* __restrict__ OutF,
    const int* __restrict__ mask, int N, int K) {
  __shared__ unsigned short As[64 * 32];
  __shared__ unsigned short Bs[128 * 32];
  const int tid = threadIdx.x;
  const int wave = tid >> 6, lane = tid & 63;
  const int lin = blockIdx.x + blockIdx.y * 512;   // 0..1023
  const int xcd = lin & 7, idx = lin >> 3;         // idx 0..127
  const int m0 = (xcd * 64 + (idx >> 1)) * 64;     // 512 row-blocks
  const int n0 = (idx & 1) * 128;                  // 2 col-blocks
  const int wm = (wave >> 1) * 32, wn = (wave & 1) * 64;

  f32x4 acc[2][4];
  #pragma unroll
  for (int i = 0; i < 2; i++)
    #pragma unroll
    for (int j = 0; j < 4; j++)
      #pragma unroll
      for (int r = 0; r < 4; r++) acc[i][j][r] = 0.f;

  const int srow = wave * 32 + (lane >> 2);
  const int skcol = (lane & 3) * 8;
  unsigned short* AsW = &As[srow * 32 + skcol];     // valid for wave<2
  unsigned short* BsW = &Bs[srow * 32 + skcol];
  const unsigned short* Ag = A + (long)(m0 + srow) * K + skcol;
  const unsigned short* Bg = B + (long)(n0 + srow) * K + skcol;

  const int fr = lane & 15, fk = (lane >> 4) * 8;

  for (int k0 = 0; k0 < K; k0 += 32) {
    if (wave < 2) {
      gl2lds16(AsW,            Ag + k0);
      gl2lds16(AsW + 16 * 32,  Ag + (long)16 * K + k0);
    }
    gl2lds16(BsW,            Bg + k0);
    gl2lds16(BsW + 16 * 32,  Bg + (long)16 * K + k0);
    __syncthreads();
    short8 af[2], bf[4];
    #pragma unroll
    for (int i = 0; i < 2; i++)
      af[i] = *(const short8*)&As[(wm + i * 16 + fr) * 32 + fk];
    #pragma unroll
    for (int j = 0; j < 4; j++)
      bf[j] = *(const short8*)&Bs[(wn + j * 16 + fr) * 32 + fk];
    #pragma unroll
    for (int i = 0; i < 2; i++)
      #pragma unroll
      for (int j = 0; j < 4; j++)
        acc[i][j] = __builtin_amdgcn_mfma_f32_16x16x32_bf16(af[i], bf[j], acc[i][j], 0, 0, 0);
    __syncthreads();
  }

  const int cl = lane & 15, rq = (lane >> 4) * 4;
  #pragma unroll
  for (int i = 0; i < 2; i++)
    #pragma unroll
    for (int j = 0; j < 4; j++) {
      int col = n0 + wn + j * 16 + cl;
      #pragma unroll
      for (int r = 0; r < 4; r++) {
        int row = m0 + wm + i * 16 + rq + r;
        long idx2 = (long)row * N + col;
        OutF[idx2] = Xres[idx2] + (mask[row] ? acc[i][j][r] : 0.f);
      }
    }
}

// ---------------- 128x48 bf16 MFMA GEMM for x_proj (K=512), fp32 out -------
__global__ __launch_bounds__(256) void gemm_n48(
    const unsigned short* __restrict__ A, const unsigned short* __restrict__ B,
    float* __restrict__ Out, int K) {
  __shared__ unsigned short As[128 * 32];
  __shared__ unsigned short Bs[48 * 32];
  const int tid = threadIdx.x;
  const int wave = tid >> 6, lane = tid & 63;
  const int m0 = blockIdx.x * 128;
  const int wm = wave * 32;

  f32x4 acc[2][3];
  #pragma unroll
  for (int i = 0; i < 2; i++)
    #pragma unroll
    for (int j = 0; j < 3; j++)
      #pragma unroll
      for (int r = 0; r < 4; r++) acc[i][j][r] = 0.f;

  const int srow = wave * 32 + (lane >> 2);
  const int skcol = (lane & 3) * 8;
  unsigned short* AsW = &As[srow * 32 + skcol];
  const unsigned short* Ag = A + (long)(m0 + srow) * K + skcol;
  const int brow = wave * 16 + (lane >> 2);   // waves 0..2 stage rows 0..47
  unsigned short* BsW = &Bs[brow * 32 + skcol];
  const unsigned short* Bg = B + (long)brow * K + skcol;

  const int fr = lane & 15, fk = (lane >> 4) * 8;

  for (int k0 = 0; k0 < K; k0 += 32) {
    gl2lds16(AsW,           Ag + k0);
    gl2lds16(AsW + 16 * 32, Ag + (long)16 * K + k0);
    if (wave < 3) gl2lds16(BsW, Bg + k0);
    __syncthreads();
    short8 af[2], bf[3];
    #pragma unroll
    for (int i = 0; i < 2; i++)
      af[i] = *(const short8*)&As[(wm + i * 16 + fr) * 32 + fk];
    #pragma unroll
    for (int j = 0; j < 3; j++)
      bf[j] = *(const short8*)&Bs[(j * 16 + fr) * 32 + fk];
    #pragma unroll
    for (int i = 0; i < 2; i++)
      #pragma unroll
      for (int j = 0; j < 3; j++)
        acc[i][j] = __builtin_amdgcn_mfma_f32_16x16x32_bf16(af[i], bf[j], acc[i][j], 0, 0, 0);
    __syncthreads();
  }

  const int cl = lane & 15, rq = (lane >> 4) * 4;
  #pragma unroll
  for (int i = 0; i < 2; i++)
    #pragma unroll
    for (int j = 0; j < 3; j++) {
      int col = j * 16 + cl;
      #pragma unroll
      for (int r = 0; r < 4; r++) {
        int row = m0 + wm + i * 16 + rq + r;
        Out[(long)row * 48 + col] = acc[i][j][r];
      }
    }
}

// ---------------- causal depthwise conv(4) + silu, 8 d per thread ----------
__global__ __launch_bounds__(256, 4) void conv_silu(
    const unsigned short* __restrict__ Upre, const float* __restrict__ cw,
    const float* __restrict__ cb, unsigned short* __restrict__ U) {
  int gid = blockIdx.x * 256 + threadIdx.x;
  int d8 = gid & 63;
  int row = gid >> 6;          // b*2048 + t (chunk-local)
  int t = row & 2047;
  int d0 = d8 * 8;
  f32x4 cwv[8];
  #pragma unroll
  for (int di = 0; di < 8; di++) cwv[di] = ((const f32x4*)(cw + (d0 + di) * 4))[0];
  f32x4 cbv0 = ((const f32x4*)(cb + d0))[0];
  f32x4 cbv1 = ((const f32x4*)(cb + d0))[1];
  float acc[8] = {cbv0.x, cbv0.y, cbv0.z, cbv0.w, cbv1.x, cbv1.y, cbv1.z, cbv1.w};
  #pragma unroll
  for (int k = 0; k < 4; k++) {
    int tt = t + k - 3;
    if (tt >= 0) {          // wave-uniform branch
      ush8 uv = *(const ush8*)(Upre + (long)(row + k - 3) * 512 + d0);
      #pragma unroll
      for (int di = 0; di < 8; di++)
        acc[di] = fmaf(b2f(uv[di]), cwv[di][k], acc[di]);
    }
  }
  ush8 o;
  #pragma unroll
  for (int di = 0; di < 8; di++) {
    float sg = 1.f / (1.f + __expf(-acc[di]));
    o[di] = f2b(acc[di] * sg);
  }
  *(ush8*)(U + (long)row * 512 + d0) = o;
}

// ---------------- scan pass 1: per-chunk end state + sum(dt) ---------------
// TWO independent chunks (c, c+32) per thread, same d: aa/w/bias shared;
// the two recurrences' loads+chains interleave at compile time, filling
// each other's stall bubbles (the per-wave ~50% duty that r2/r7/r8/r9
// could not move). (256,3): VGPR cap 170, no spill possible (r3 lesson);
// 12 waves/CU x 2x ILP vs measured 16-wave cap.
template<int DTM>
__global__ __launch_bounds__(256, 3) void scan_p1(
    const unsigned short* __restrict__ U, const float* __restrict__ XD,
    const float* __restrict__ AA, const float* __restrict__ dtw,
    const float* __restrict__ dtb, float* __restrict__ HCH,
    float* __restrict__ DTS, _Float16* __restrict__ DTH) {
  int gid = blockIdx.x * 256 + threadIdx.x;
  int d = gid & 511;
  int pc = gid >> 9;                 // b*32 + c, c in [0,32)
  int c = pc & 31, b = pc >> 5;
  f32x4 aa0 = ld4(AA + d * 16),      aa1 = ld4(AA + d * 16 + 4),
        aa2 = ld4(AA + d * 16 + 8),  aa3 = ld4(AA + d * 16 + 12);
  f32x4 w0 = ld4(dtw + d * 16),      w1 = ld4(dtw + d * 16 + 4),
        w2 = ld4(dtw + d * 16 + 8),  w3 = ld4(dtw + d * 16 + 12);
  asm volatile("s_waitcnt vmcnt(0)"
               : "+v"(aa0), "+v"(aa1), "+v"(aa2), "+v"(aa3),
                 "+v"(w0), "+v"(w1), "+v"(w2), "+v"(w3));
  f32x4 hA0 = {0.f,0.f,0.f,0.f}, hA1 = hA0, hA2 = hA0, hA3 = hA0;
  f32x4 hB0 = hA0, hB1 = hA0, hB2 = hA0, hB3 = hA0;
  float bias = dtb[d];
  float dtsA = 0.f, dtsB = 0.f;
  int rowA = b * 2048 + c * 32;
  int rowB = rowA + 1024;            // chunk c+32
  const unsigned short* UpA = U + (long)rowA * 512 + d;
  const unsigned short* UpB = U + (long)rowB * 512 + d;
  _Float16* DTpA = DTH + (long)rowA * 512 + d;
  _Float16* DTpB = DTH + (long)rowB * 512 + d;
  for (int tt = 0; tt < 32; tt++) {
    int offA = __builtin_amdgcn_readfirstlane(rowA * 48);
    int offB = __builtin_amdgcn_readfirstlane(rowB * 48);
    const f32x4* xsA = (const f32x4*)(XD + offA);
    const f32x4* xsB = (const f32x4*)(XD + offB);
    unsigned short uA = *UpA, uB = *UpB;
    // dt for both streams first (frees x regs before B/h phase)
    f32x4 xA0 = xsA[0], xA1 = xsA[1], xA2 = xsA[2], xA3 = xsA[3];
    f32x4 xB0 = xsB[0], xB1 = xsB[1], xB2 = xsB[2], xB3 = xsB[3];
    f32x4 ppA = xA0 * w0 + xA1 * w1 + xA2 * w2 + xA3 * w3;
    f32x4 ppB = xB0 * w0 + xB1 * w1 + xB2 * w2 + xB3 * w3;
    float sA = bias + ppA.x + ppA.y + ppA.z + ppA.w;
    float sB = bias + ppB.x + ppB.y + ppB.z + ppB.w;
    float eA = __expf(-fabsf(sA));
    float eB = __expf(-fabsf(sB));
    float dtA = fmaxf(sA, 0.f) + __logf(1.f + eA);
    float dtB = fmaxf(sB, 0.f) + __logf(1.f + eB);
    if (DTM) { *DTpA = (_Float16)dtA; *DTpB = (_Float16)dtB; }
    float duA = dtA * b2f(uA);
    float duB = dtB * b2f(uB);
    f32x4 BA0 = xsA[4], BA1 = xsA[5], BA2 = xsA[6], BA3 = xsA[7];
    f32x4 BB0 = xsB[4], BB1 = xsB[5], BB2 = xsB[6], BB3 = xsB[7];
    hA0 = exp2v(dtA * aa0) * hA0 + duA * BA0;
    hB0 = exp2v(dtB * aa0) * hB0 + duB * BB0;
    hA1 = exp2v(dtA * aa1) * hA1 + duA * BA1;
    hB1 = exp2v(dtB * aa1) * hB1 + duB * BB1;
    hA2 = exp2v(dtA * aa2) * hA2 + duA * BA2;
    hB2 = exp2v(dtB * aa2) * hB2 + duB * BB2;
    hA3 = exp2v(dtA * aa3) * hA3 + duA * BA3;
    hB3 = exp2v(dtB * aa3) * hB3 + duB * BB3;
    dtsA += dtA; dtsB += dtB;
    rowA++; rowB++; UpA += 512; UpB += 512; DTpA += 512; DTpB += 512;
  }
  long gidA = ((long)b * 64 + c) * 512 + d;
  long gidB = gidA + 32 * 512;
  f32x4* hpA = (f32x4*)(HCH + gidA * 16);
  hpA[0] = hA0; hpA[1] = hA1; hpA[2] = hA2; hpA[3] = hA3;
  f32x4* hpB = (f32x4*)(HCH + gidB * 16);
  hpB[0] = hB0; hpB[1] = hB1; hpB[2] = hB2; hpB[3] = hB3;
  DTS[gidA] = dtsA;
  DTS[gidB] = dtsB;
}

// ---------------- scan pass 2: prefix over chunks (h_end -> h_start) -------
// unroll-4: the 4 loads + 4 exps are independent of the serial fma chain;
// batching them ahead breaks the per-iteration load-latency chain (p2 runs
// at only ~2 waves/SIMD — latency-bound).
__global__ __launch_bounds__(256) void scan_p2(
    float* __restrict__ HCH, const float* __restrict__ DTS,
    const float* __restrict__ AA) {
  int gid = blockIdx.x * 256 + threadIdx.x;   // b*8192 + d*16 + n
  int n = gid & 15;
  int d = (gid >> 4) & 511;
  int b = gid >> 13;
  float aa = AA[d * 16 + n];
  float hrun = 0.f;
  for (int c4 = 0; c4 < 64; c4 += 4) {
    float he0, he1, he2, he3, P0, P1, P2, P3;
    long i0, i1, i2, i3;
    {
      long base0 = ((long)b * 64 + c4 + 0) * 512 + d;
      long base1 = ((long)b * 64 + c4 + 1) * 512 + d;
      long base2 = ((long)b * 64 + c4 + 2) * 512 + d;
      long base3 = ((long)b * 64 + c4 + 3) * 512 + d;
      i0 = base0 * 16 + n; i1 = base1 * 16 + n;
      i2 = base2 * 16 + n; i3 = base3 * 16 + n;
      he0 = HCH[i0]; he1 = HCH[i1]; he2 = HCH[i2]; he3 = HCH[i3];
      P0 = ex2(DTS[base0] * aa); P1 = ex2(DTS[base1] * aa);
      P2 = ex2(DTS[base2] * aa); P3 = ex2(DTS[base3] * aa);
    }
    HCH[i0] = hrun; hrun = fmaf(P0, hrun, he0);
    HCH[i1] = hrun; hrun = fmaf(P1, hrun, he1);
    HCH[i2] = hrun; hrun = fmaf(P2, hrun, he2);
    HCH[i3] = hrun; hrun = fmaf(P3, hrun, he3);
  }
}

// ---------------- scan pass 3: replay with h_start, fused gate -------------
// Y may alias U (same-thread same-element read-before-write)
// DTM: load dt (fp16, written by p1). Two chunks per thread (see scan_p1).
template<int DTM>
__global__ __launch_bounds__(256, 3) void scan_p3(
    const unsigned short* __restrict__ U, const unsigned short* __restrict__ Z,
    const float* __restrict__ XD, const float* __restrict__ AA,
    const float* __restrict__ dtw, const float* __restrict__ dtb,
    const float* __restrict__ HCH, const float* __restrict__ skD,
    unsigned short* __restrict__ Y, const _Float16* __restrict__ DTH) {
  int gid = blockIdx.x * 256 + threadIdx.x;
  int d = gid & 511;
  int pc = gid >> 9;
  int c = pc & 31, b = pc >> 5;
  f32x4 aa0 = ld4(AA + d * 16),      aa1 = ld4(AA + d * 16 + 4),
        aa2 = ld4(AA + d * 16 + 8),  aa3 = ld4(AA + d * 16 + 12);
  f32x4 w0, w1, w2, w3;
  if (!DTM) {
    w0 = ld4(dtw + d * 16);     w1 = ld4(dtw + d * 16 + 4);
    w2 = ld4(dtw + d * 16 + 8); w3 = ld4(dtw + d * 16 + 12);
    asm volatile("s_waitcnt vmcnt(0)"
                 : "+v"(aa0), "+v"(aa1), "+v"(aa2), "+v"(aa3),
                   "+v"(w0), "+v"(w1), "+v"(w2), "+v"(w3));
  } else {
    asm volatile("s_waitcnt vmcnt(0)"
                 : "+v"(aa0), "+v"(aa1), "+v"(aa2), "+v"(aa3));
  }
  long gidA = ((long)b * 64 + c) * 512 + d;
  long gidB = gidA + 32 * 512;
  f32x4 hA0, hA1, hA2, hA3, hB0, hB1, hB2, hB3;
  {
    const f32x4* hpA = (const f32x4*)(HCH + gidA * 16);
    hA0 = hpA[0]; hA1 = hpA[1]; hA2 = hpA[2]; hA3 = hpA[3];
    const f32x4* hpB = (const f32x4*)(HCH + gidB * 16);
    hB0 = hpB[0]; hB1 = hpB[1]; hB2 = hpB[2]; hB3 = hpB[3];
  }
  float bias = DTM ? 0.f : dtb[d];
  float sD = skD[d];
  int rowA = b * 2048 + c * 32;
  int rowB = rowA + 1024;
  const unsigned short* UpA = U + (long)rowA * 512 + d;
  const unsigned short* UpB = U + (long)rowB * 512 + d;
  const unsigned short* ZpA = Z + (long)rowA * 512 + d;
  const unsigned short* ZpB = Z + (long)rowB * 512 + d;
  unsigned short* YpA = Y + (long)rowA * 512 + d;
  unsigned short* YpB = Y + (long)rowB * 512 + d;
  const _Float16* DTpA = DTH + (long)rowA * 512 + d;
  const _Float16* DTpB = DTH + (long)rowB * 512 + d;
  for (int tt = 0; tt < 32; tt++) {
    int offA = __builtin_amdgcn_readfirstlane(rowA * 48);
    int offB = __builtin_amdgcn_readfirstlane(rowB * 48);
    const f32x4* xsA = (const f32x4*)(XD + offA);
    const f32x4* xsB = (const f32x4*)(XD + offB);
    unsigned short uA16 = *UpA, uB16 = *UpB;
    unsigned short zA16 = *ZpA, zB16 = *ZpB;
    float dtA, dtB;
    if (DTM) {
      dtA = (float)*DTpA;
      dtB = (float)*DTpB;
    } else {
      f32x4 xA0 = xsA[0], xA1 = xsA[1], xA2 = xsA[2], xA3 = xsA[3];
      f32x4 ppA = xA0 * w0 + xA1 * w1 + xA2 * w2 + xA3 * w3;
      float sA = bias + ppA.x + ppA.y + ppA.z + ppA.w;
      float eA = __expf(-fabsf(sA));
      dtA = fmaxf(sA, 0.f) + __logf(1.f + eA);
      f32x4 xB0 = xsB[0], xB1 = xsB[1], xB2 = xsB[2], xB3 = xsB[3];
      f32x4 ppB = xB0 * w0 + xB1 * w1 + xB2 * w2 + xB3 * w3;
      float sB = bias + ppB.x + ppB.y + ppB.z + ppB.w;
      float eB = __expf(-fabsf(sB));
      dtB = fmaxf(sB, 0.f) + __logf(1.f + eB);
    }
    float uA = b2f(uA16), uB = b2f(uB16);
    float duA = dtA * uA, duB = dtB * uB;
    // stream A h-update + output
    {
      f32x4 BA0 = xsA[4], BA1 = xsA[5], BA2 = xsA[6], BA3 = xsA[7];
      f32x4 CA0 = xsA[8], CA1 = xsA[9], CA2 = xsA[10], CA3 = xsA[11];
      hA0 = exp2v(dtA * aa0) * hA0 + duA * BA0;
      hA1 = exp2v(dtA * aa1) * hA1 + duA * BA1;
      hA2 = exp2v(dtA * aa2) * hA2 + duA * BA2;
      hA3 = exp2v(dtA * aa3) * hA3 + duA * BA3;
      f32x4 yv = hA0 * CA0 + hA1 * CA1 + hA2 * CA2 + hA3 * CA3;
      float y = yv.x + yv.y + yv.z + yv.w + uA * sD;
      float z = b2f(zA16);
      float sg = z / (1.f + __expf(-z));
      *YpA = f2b(y * sg);
    }
    // stream B h-update + output
    {
      f32x4 BB0 = xsB[4], BB1 = xsB[5], BB2 = xsB[6], BB3 = xsB[7];
      f32x4 CB0 = xsB[8], CB1 = xsB[9], CB2 = xsB[10], CB3 = xsB[11];
      hB0 = exp2v(dtB * aa0) * hB0 + duB * BB0;
      hB1 = exp2v(dtB * aa1) * hB1 + duB * BB1;
      hB2 = exp2v(dtB * aa2) * hB2 + duB * BB2;
      hB3 = exp2v(dtB * aa3) * hB3 + duB * BB3;
      f32x4 yv = hB0 * CB0 + hB1 * CB1 + hB2 * CB2 + hB3 * CB3;
      float y = yv.x + yv.y + yv.z + yv.w + uB * sD;
      float z = b2f(zB16);
      float sg = z / (1.f + __expf(-z));
      *YpB = f2b(y * sg);
    }
    rowA++; rowB++;
    UpA += 512; UpB += 512; ZpA += 512; ZpB += 512;
    YpA += 512; YpB += 512; DTpA += 512; DTpB += 512;
  }
}

extern "C" void kernel_launch(void* const* d_in, const int* in_sizes, int n_in,
                              void* d_out, int out_size, void* d_ws, size_t ws_size,
                              hipStream_t stream) {
  const float* x        = (const float*)d_in[0];
  const int*   mask     = (const int*)d_in[1];
  const float* ln_w     = (const float*)d_in[2];
  const float* ln_b     = (const float*)d_in[3];
  const float* in_proj  = (const float*)d_in[4];
  const float* conv_w   = (const float*)d_in[5];
  const float* conv_b   = (const float*)d_in[6];
  const float* x_proj   = (const float*)d_in[7];
  const float* dt_w     = (const float*)d_in[8];
  const float* dt_b     = (const float*)d_in[9];
  const float* A_log    = (const float*)d_in[10];
  const float* skip_D   = (const float*)d_in[11];
  const float* out_proj = (const float*)d_in[12];
  float* X = (float*)d_out;

  // ---- workspace layout (~114 MB base, +33.5 MB DT when ws allows) ----
  char* p = (char*)d_ws;
  auto alloc = [&](size_t n) { char* r = p; p += (n + 255) & ~(size_t)255; return r; };
  unsigned short* WBin  = (unsigned short*)alloc((size_t)2 * 1024 * 256 * 2);  // 1 MB
  unsigned short* WBx   = (unsigned short*)alloc((size_t)2 * 48 * 512 * 2);
  unsigned short* WBout = (unsigned short*)alloc((size_t)2 * 256 * 512 * 2);
  float*          AA    = (float*)alloc((size_t)2 * 512 * 16 * 4);
  char* R_XN   = alloc((size_t)RC * 256 * 2);        // 16 MB: XN, then XD+DTS
  char* R_UPRE = alloc((size_t)RC * 512 * 2);        // 32 MB: Upre, then HCH
  char* R_Z    = alloc((size_t)RC * 512 * 2);        // 32 MB: Z
  char* R_U    = alloc((size_t)RC * 512 * 2);        // 32 MB: U (=Y in-place)
  char* R_DT   = alloc((size_t)RC * 512 * 2);        // 32 MB: dt fp16 (optional)

  unsigned short* XN   = (unsigned short*)R_XN;
  float*          XD   = (float*)R_XN;                         // after in_proj
  float*          DTS  = (float*)(R_XN + 8388608);             // 2 MB @ +8 MB
  unsigned short* Upre = (unsigned short*)R_UPRE;
  float*          HCH  = (float*)R_UPRE;                       // after conv
  unsigned short* Z    = (unsigned short*)R_Z;
  unsigned short* U    = (unsigned short*)R_U;
  _Float16*       DTH  = (_Float16*)R_DT;

  // dt-persist path needs the whole layout incl. R_DT to fit the workspace
  const bool use_dt = ws_size >= (size_t)((char*)p - (char*)d_ws);

  prep_weights<<<3328, 256, 0, stream>>>(in_proj, x_proj, out_proj, A_log,
                                         WBin, WBx, WBout, AA);

  for (int ch = 0; ch < 2; ch++) {
    const long row0 = (long)ch * RC;
    float* Xc = X + row0 * 256;
    const int* maskc = mask + row0;
    for (int i = 0; i < 2; i++) {
      if (i == 0) {
        // layer 0: mask + write masked residual X + LN, one pass
        ln_mask_fwd<<<RC / 4, 256, 0, stream>>>(x + row0 * 256, maskc,
            ln_w, ln_b, Xc, XN);
      } else {
        ln_fwd<<<RC / 4, 256, 0, stream>>>(Xc, ln_w + i * 256, ln_b + i * 256, XN);
      }
      gemm128<<<dim3(RC / 128, 8), 256, 0, stream>>>(XN, WBin + i * 262144,
          Upre, Z, 1024, 256);
      conv_silu<<<RC / 4, 256, 0, stream>>>(Upre, conv_w + i * 2048,
          conv_b + i * 512, U);
      gemm_n48<<<RC / 128, 256, 0, stream>>>(U, WBx + i * 24576, XD, 512);
      if (use_dt) {
        scan_p1<1><<<BCH * 64, 256, 0, stream>>>(U, XD, AA + i * 8192,
            dt_w + i * 8192, dt_b + i * 512, HCH, DTS, DTH);
      } else {
        scan_p1<0><<<BCH * 64, 256, 0, stream>>>(U, XD, AA + i * 8192,
            dt_w + i * 8192, dt_b + i * 512, HCH, DTS, DTH);
      }
      scan_p2<<<BCH * 32, 256, 0, stream>>>(HCH, DTS, AA + i * 8192);
      if (use_dt) {
        scan_p3<1><<<BCH * 64, 256, 0, stream>>>(U, Z, XD, AA + i * 8192,
            dt_w + i * 8192, dt_b + i * 512, HCH, skip_D + i * 512, U, DTH);
      } else {
        scan_p3<0><<<BCH * 64, 256, 0, stream>>>(U, Z, XD, AA + i * 8192,
            dt_w + i * 8192, dt_b + i * 512, HCH, skip_D + i * 512, U, DTH);
      }
      gemm64<<<dim3(RC / 64, 2), 256, 0, stream>>>(U, WBout + i * 131072,
          Xc, Xc, maskc, 256, 512);
    }
  }
}

// Round 13
// 1093.923 us; speedup vs baseline: 1.0396x; 1.0396x over previous
//
#include <hip/hip_runtime.h>
#include <cstdint>

#define LOG2E 1.4426950408889634f
#define BCH 16                 // batches per chunk
#define RC  (BCH * 2048)       // rows per chunk = 32768

typedef __attribute__((ext_vector_type(8))) short short8;
typedef __attribute__((ext_vector_type(4))) float f32x4;
typedef __attribute__((ext_vector_type(4))) unsigned short ush4;
typedef __attribute__((ext_vector_type(8))) unsigned short ush8;

__device__ __forceinline__ float b2f(unsigned short u) {
  union { unsigned int u; float f; } c; c.u = ((unsigned int)u) << 16; return c.f;
}
__device__ __forceinline__ unsigned short f2b(float f) {
  union { float f; unsigned int u; } c; c.f = f;
  unsigned int r = c.u + 0x7FFFu + ((c.u >> 16) & 1u);
  return (unsigned short)(r >> 16);
}
// HW exp2 (exp2f goes through OCML). Scan ledger: r4 poly-exp2 regressed
// (trans not saturated); r5/r6 packed fp32 dead (asm NaN / compiler slower);
// r2 pipeline null; r7/r8 launch-shape null; r9 XD-LDS null; r12 2-chunk ILP
// regressed (waves x duty pinned). Conclusion: scans run at ~80-85% of the
// VALU+trans ISSUE roofline (~190 VALU + 19 trans per step); single-chunk
// form is the measured optimum. Do not re-derive these levers.
__device__ __forceinline__ float ex2(float x) { return __builtin_amdgcn_exp2f(x); }
__device__ __forceinline__ f32x4 exp2v(f32x4 v) {
  f32x4 r; r.x = ex2(v.x); r.y = ex2(v.y); r.z = ex2(v.z); r.w = ex2(v.w);
  return r;
}

// opaque 16B load: result cannot be rematerialized -> stays in VGPRs
__device__ __forceinline__ f32x4 ld4(const float* p) {
  f32x4 r;
  asm volatile("global_load_dwordx4 %0, %1, off" : "=v"(r) : "v"(p));
  return r;
}

// async global->LDS, 16B/lane; LDS dest contiguous in lane order (base+lane*16B)
__device__ __forceinline__ void gl2lds16(void* l, const void* g) {
  __builtin_amdgcn_global_load_lds(
      (const __attribute__((address_space(1))) void*)g,
      (__attribute__((address_space(3))) void*)l, 16, 0, 0);
}

// ---------------- weight prep: fp32 -> bf16, and AA = -exp(A_log)*log2e ----
__global__ __launch_bounds__(256) void prep_weights(
    const float* __restrict__ inw, const float* __restrict__ xw,
    const float* __restrict__ ow, const float* __restrict__ alog,
    unsigned short* __restrict__ inwb, unsigned short* __restrict__ xwb,
    unsigned short* __restrict__ owb, float* __restrict__ AA) {
  int gid = blockIdx.x * 256 + threadIdx.x;
  const int n_in = 2 * 1024 * 256;   // 524288
  const int n_x  = 2 * 48 * 512;     // 49152
  const int n_o  = 2 * 256 * 512;    // 262144
  const int n_a  = 2 * 512 * 16;     // 16384
  if (gid < n_in) { inwb[gid] = f2b(inw[gid]); return; }
  gid -= n_in;
  if (gid < n_x) { xwb[gid] = f2b(xw[gid]); return; }
  gid -= n_x;
  if (gid < n_o) { owb[gid] = f2b(ow[gid]); return; }
  gid -= n_o;
  if (gid < n_a) { AA[gid] = -__expf(alog[gid]) * LOG2E; }
}

// ---------------- LayerNorm: one wave per row, X fp32 -> XN bf16 -----------
__global__ __launch_bounds__(256) void ln_fwd(
    const float* __restrict__ X, const float* __restrict__ w,
    const float* __restrict__ b, unsigned short* __restrict__ XN) {
  int wv = threadIdx.x >> 6, ln = threadIdx.x & 63;
  long row = (long)blockIdx.x * 4 + wv;
  f32x4 v = ((const f32x4*)(X + row * 256))[ln];
  float s = v.x + v.y + v.z + v.w;
  float s2 = v.x * v.x + v.y * v.y + v.z * v.z + v.w * v.w;
  #pragma unroll
  for (int o = 32; o > 0; o >>= 1) {
    s += __shfl_xor(s, o, 64);
    s2 += __shfl_xor(s2, o, 64);
  }
  float mu = s * (1.f / 256.f);
  float var = s2 * (1.f / 256.f) - mu * mu;
  float rst = rsqrtf(var + 1e-5f);
  f32x4 wv4 = ((const f32x4*)w)[ln];
  f32x4 bv4 = ((const f32x4*)b)[ln];
  ush4 o4;
  o4.x = f2b((v.x - mu) * rst * wv4.x + bv4.x);
  o4.y = f2b((v.y - mu) * rst * wv4.y + bv4.y);
  o4.z = f2b((v.z - mu) * rst * wv4.z + bv4.z);
  o4.w = f2b((v.w - mu) * rst * wv4.w + bv4.w);
  ((ush4*)(XN + row * 256))[ln] = o4;
}

// ---------------- layer-0 LN: mask + write masked residual X + LN ----------
// Replaces the standalone mask_x pass (268 MB of traffic): reads raw x,
// zeroes masked rows (wave-uniform), writes the masked X (residual base for
// gemm64) and the LN output in one sweep. (kept from r12: orthogonal win)
__global__ __launch_bounds__(256) void ln_mask_fwd(
    const float* __restrict__ Xin, const int* __restrict__ mask,
    const float* __restrict__ w, const float* __restrict__ b,
    float* __restrict__ Xout, unsigned short* __restrict__ XN) {
  int wv = threadIdx.x >> 6, ln = threadIdx.x & 63;
  long row = (long)blockIdx.x * 4 + wv;
  f32x4 v = ((const f32x4*)(Xin + row * 256))[ln];
  if (!mask[row]) { v.x = 0.f; v.y = 0.f; v.z = 0.f; v.w = 0.f; }
  ((f32x4*)(Xout + row * 256))[ln] = v;
  float s = v.x + v.y + v.z + v.w;
  float s2 = v.x * v.x + v.y * v.y + v.z * v.z + v.w * v.w;
  #pragma unroll
  for (int o = 32; o > 0; o >>= 1) {
    s += __shfl_xor(s, o, 64);
    s2 += __shfl_xor(s2, o, 64);
  }
  float mu = s * (1.f / 256.f);
  float var = s2 * (1.f / 256.f) - mu * mu;
  float rst = rsqrtf(var + 1e-5f);
  f32x4 wv4 = ((const f32x4*)w)[ln];
  f32x4 bv4 = ((const f32x4*)b)[ln];
  ush4 o4;
  o4.x = f2b((v.x - mu) * rst * wv4.x + bv4.x);
  o4.y = f2b((v.y - mu) * rst * wv4.y + bv4.y);
  o4.z = f2b((v.z - mu) * rst * wv4.z + bv4.z);
  o4.w = f2b((v.w - mu) * rst * wv4.w + bv4.w);
  ((ush4*)(XN + row * 256))[ln] = o4;
}

// ---------------- 128x128 bf16 MFMA GEMM, C = A(MxK) * B(NxK)^T ------------
// split store bf16: col<512 -> OutU, else OutZ (for in_proj)
// XCD-chunked block swizzle: the 8 sharers of an A panel co-resident on 1 XCD.
__global__ __launch_bounds__(256) void gemm128(
    const unsigned short* __restrict__ A, const unsigned short* __restrict__ B,
    unsigned short* __restrict__ OutU, unsigned short* __restrict__ OutZ,
    int N, int K) {
  __shared__ unsigned short As[128 * 32];
  __shared__ unsigned short Bs[128 * 32];
  const int tid = threadIdx.x;
  const int wave = tid >> 6, lane = tid & 63;
  const int lin = blockIdx.x + blockIdx.y * 256;   // dispatch order, 0..2047
  const int xcd = lin & 7, idx = lin >> 3;
  const int m0 = (xcd * 32 + (idx >> 3)) * 128;    // 256 row-blocks
  const int n0 = (idx & 7) * 128;                  // 8 col-blocks
  const int wm = (wave >> 1) * 64, wn = (wave & 1) * 64;

  f32x4 acc[4][4];
  #pragma unroll
  for (int i = 0; i < 4; i++)
    #pragma unroll
    for (int j = 0; j < 4; j++)
      #pragma unroll
      for (int r = 0; r < 4; r++) acc[i][j][r] = 0.f;

  const int srow = wave * 32 + (lane >> 2);
  const int skcol = (lane & 3) * 8;
  unsigned short* AsW = &As[srow * 32 + skcol];
  unsigned short* BsW = &Bs[srow * 32 + skcol];
  const unsigned short* Ag = A + (long)(m0 + srow) * K + skcol;
  const unsigned short* Bg = B + (long)(n0 + srow) * K + skcol;

  const int fr = lane & 15, fk = (lane >> 4) * 8;

  for (int k0 = 0; k0 < K; k0 += 32) {
    gl2lds16(AsW,            Ag + k0);
    gl2lds16(AsW + 16 * 32,  Ag + (long)16 * K + k0);
    gl2lds16(BsW,            Bg + k0);
    gl2lds16(BsW + 16 * 32,  Bg + (long)16 * K + k0);
    __syncthreads();
    short8 af[4], bf[4];
    #pragma unroll
    for (int i = 0; i < 4; i++) {
      af[i] = *(const short8*)&As[(wm + i * 16 + fr) * 32 + fk];
      bf[i] = *(const short8*)&Bs[(wn + i * 16 + fr) * 32 + fk];
    }
    #pragma unroll
    for (int i = 0; i < 4; i++)
      #pragma unroll
      for (int j = 0; j < 4; j++)
        acc[i][j] = __builtin_amdgcn_mfma_f32_16x16x32_bf16(af[i], bf[j], acc[i][j], 0, 0, 0);
    __syncthreads();
  }

  const int cl = lane & 15, rq = (lane >> 4) * 4;
  #pragma unroll
  for (int i = 0; i < 4; i++)
    #pragma unroll
    for (int j = 0; j < 4; j++) {
      int col = n0 + wn + j * 16 + cl;
      #pragma unroll
      for (int r = 0; r < 4; r++) {
        int row = m0 + wm + i * 16 + rq + r;
        float v = acc[i][j][r];
        if (col < 512) OutU[(long)row * 512 + col] = f2b(v);
        else           OutZ[(long)row * 512 + (col - 512)] = f2b(v);
      }
    }
}

// ---------------- 64x128 bf16 MFMA GEMM for out_proj (more blocks/CU) ------
// OutF[row*N+col] = Xres[row*N+col] + (mask[row] ? acc : 0)
__global__ __launch_bounds__(256) void gemm64(
    const unsigned short* __restrict__ A, const unsigned short* __restrict__ B,
    const float* __restrict__ Xres, float* __restrict__ OutF,
    const int* __restrict__ mask, int N, int K) {
  __shared__ unsigned short As[64 * 32];
  __shared__ unsigned short Bs[128 * 32];
  const int tid = threadIdx.x;
  const int wave = tid >> 6, lane = tid & 63;
  const int lin = blockIdx.x + blockIdx.y * 512;   // 0..1023
  const int xcd = lin & 7, idx = lin >> 3;         // idx 0..127
  const int m0 = (xcd * 64 + (idx >> 1)) * 64;     // 512 row-blocks
  const int n0 = (idx & 1) * 128;                  // 2 col-blocks
  const int wm = (wave >> 1) * 32, wn = (wave & 1) * 64;

  f32x4 acc[2][4];
  #pragma unroll
  for (int i = 0; i < 2; i++)
    #pragma unroll
    for (int j = 0; j < 4; j++)
      #pragma unroll
      for (int r = 0; r < 4; r++) acc[i][j][r] = 0.f;

  const int srow = wave * 32 + (lane >> 2);
  const int skcol = (lane & 3) * 8;
  unsigned short* AsW = &As[srow * 32 + skcol];     // valid for wave<2
  unsigned short* BsW = &Bs[srow * 32 + skcol];
  const unsigned short* Ag = A + (long)(m0 + srow) * K + skcol;
  const unsigned short* Bg = B + (long)(n0 + srow) * K + skcol;

  const int fr = lane & 15, fk = (lane >> 4) * 8;

  for (int k0 = 0; k0 < K; k0 += 32) {
    if (wave < 2) {
      gl2lds16(AsW,            Ag + k0);
      gl2lds16(AsW + 16 * 32,  Ag + (long)16 * K + k0);
    }
    gl2lds16(BsW,            Bg + k0);
    gl2lds16(BsW + 16 * 32,  Bg + (long)16 * K + k0);
    __syncthreads();
    short8 af[2], bf[4];
    #pragma unroll
    for (int i = 0; i < 2; i++)
      af[i] = *(const short8*)&As[(wm + i * 16 + fr) * 32 + fk];
    #pragma unroll
    for (int j = 0; j < 4; j++)
      bf[j] = *(const short8*)&Bs[(wn + j * 16 + fr) * 32 + fk];
    #pragma unroll
    for (int i = 0; i < 2; i++)
      #pragma unroll
      for (int j = 0; j < 4; j++)
        acc[i][j] = __builtin_amdgcn_mfma_f32_16x16x32_bf16(af[i], bf[j], acc[i][j], 0, 0, 0);
    __syncthreads();
  }

  const int cl = lane & 15, rq = (lane >> 4) * 4;
  #pragma unroll
  for (int i = 0; i < 2; i++)
    #pragma unroll
    for (int j = 0; j < 4; j++) {
      int col = n0 + wn + j * 16 + cl;
      #pragma unroll
      for (int r = 0; r < 4; r++) {
        int row = m0 + wm + i * 16 + rq + r;
        long idx2 = (long)row * N + col;
        OutF[idx2] = Xres[idx2] + (mask[row] ? acc[i][j][r] : 0.f);
      }
    }
}

// ---------------- 128x48 bf16 MFMA GEMM for x_proj (K=512), fp32 out -------
__global__ __launch_bounds__(256) void gemm_n48(
    const unsigned short* __restrict__ A, const unsigned short* __restrict__ B,
    float* __restrict__ Out, int K) {
  __shared__ unsigned short As[128 * 32];
  __shared__ unsigned short Bs[48 * 32];
  const int tid = threadIdx.x;
  const int wave = tid >> 6, lane = tid & 63;
  const int m0 = blockIdx.x * 128;
  const int wm = wave * 32;

  f32x4 acc[2][3];
  #pragma unroll
  for (int i = 0; i < 2; i++)
    #pragma unroll
    for (int j = 0; j < 3; j++)
      #pragma unroll
      for (int r = 0; r < 4; r++) acc[i][j][r] = 0.f;

  const int srow = wave * 32 + (lane >> 2);
  const int skcol = (lane & 3) * 8;
  unsigned short* AsW = &As[srow * 32 + skcol];
  const unsigned short* Ag = A + (long)(m0 + srow) * K + skcol;
  const int brow = wave * 16 + (lane >> 2);   // waves 0..2 stage rows 0..47
  unsigned short* BsW = &Bs[brow * 32 + skcol];
  const unsigned short* Bg = B + (long)brow * K + skcol;

  const int fr = lane & 15, fk = (lane >> 4) * 8;

  for (int k0 = 0; k0 < K; k0 += 32) {
    gl2lds16(AsW,           Ag + k0);
    gl2lds16(AsW + 16 * 32, Ag + (long)16 * K + k0);
    if (wave < 3) gl2lds16(BsW, Bg + k0);
    __syncthreads();
    short8 af[2], bf[3];
    #pragma unroll
    for (int i = 0; i < 2; i++)
      af[i] = *(const short8*)&As[(wm + i * 16 + fr) * 32 + fk];
    #pragma unroll
    for (int j = 0; j < 3; j++)
      bf[j] = *(const short8*)&Bs[(j * 16 + fr) * 32 + fk];
    #pragma unroll
    for (int i = 0; i < 2; i++)
      #pragma unroll
      for (int j = 0; j < 3; j++)
        acc[i][j] = __builtin_amdgcn_mfma_f32_16x16x32_bf16(af[i], bf[j], acc[i][j], 0, 0, 0);
    __syncthreads();
  }

  const int cl = lane & 15, rq = (lane >> 4) * 4;
  #pragma unroll
  for (int i = 0; i < 2; i++)
    #pragma unroll
    for (int j = 0; j < 3; j++) {
      int col = j * 16 + cl;
      #pragma unroll
      for (int r = 0; r < 4; r++) {
        int row = m0 + wm + i * 16 + rq + r;
        Out[(long)row * 48 + col] = acc[i][j][r];
      }
    }
}

// ---------------- causal depthwise conv(4) + silu, 8 d per thread ----------
__global__ __launch_bounds__(256, 4) void conv_silu(
    const unsigned short* __restrict__ Upre, const float* __restrict__ cw,
    const float* __restrict__ cb, unsigned short* __restrict__ U) {
  int gid = blockIdx.x * 256 + threadIdx.x;
  int d8 = gid & 63;
  int row = gid >> 6;          // b*2048 + t (chunk-local)
  int t = row & 2047;
  int d0 = d8 * 8;
  f32x4 cwv[8];
  #pragma unroll
  for (int di = 0; di < 8; di++) cwv[di] = ((const f32x4*)(cw + (d0 + di) * 4))[0];
  f32x4 cbv0 = ((const f32x4*)(cb + d0))[0];
  f32x4 cbv1 = ((const f32x4*)(cb + d0))[1];
  float acc[8] = {cbv0.x, cbv0.y, cbv0.z, cbv0.w, cbv1.x, cbv1.y, cbv1.z, cbv1.w};
  #pragma unroll
  for (int k = 0; k < 4; k++) {
    int tt = t + k - 3;
    if (tt >= 0) {          // wave-uniform branch
      ush8 uv = *(const ush8*)(Upre + (long)(row + k - 3) * 512 + d0);
      #pragma unroll
      for (int di = 0; di < 8; di++)
        acc[di] = fmaf(b2f(uv[di]), cwv[di][k], acc[di]);
    }
  }
  ush8 o;
  #pragma unroll
  for (int di = 0; di < 8; di++) {
    float sg = 1.f / (1.f + __expf(-acc[di]));
    o[di] = f2b(acc[di] * sg);
  }
  *(ush8*)(U + (long)row * 512 + d0) = o;
}

// ---------------- scan pass 1: per-chunk end state + sum(dt) ---------------
// DTM: additionally persist dt (fp16) so scan_p3 need not recompute it.
// Single-chunk form: measured optimum (r12 ILP A/B regressed; see ledger).
template<int DTM>
__global__ __launch_bounds__(256, 4) void scan_p1(
    const unsigned short* __restrict__ U, const float* __restrict__ XD,
    const float* __restrict__ AA, const float* __restrict__ dtw,
    const float* __restrict__ dtb, float* __restrict__ HCH,
    float* __restrict__ DTS, _Float16* __restrict__ DTH) {
  int gid = blockIdx.x * 256 + threadIdx.x;
  int d = gid & 511;
  int bc = gid >> 9;
  int c = bc & 63, b = bc >> 6;
  // opaque loads: values must live in VGPRs (no remat from global in the loop)
  f32x4 aa0 = ld4(AA + d * 16),      aa1 = ld4(AA + d * 16 + 4),
        aa2 = ld4(AA + d * 16 + 8),  aa3 = ld4(AA + d * 16 + 12);
  f32x4 w0 = ld4(dtw + d * 16),      w1 = ld4(dtw + d * 16 + 4),
        w2 = ld4(dtw + d * 16 + 8),  w3 = ld4(dtw + d * 16 + 12);
  asm volatile("s_waitcnt vmcnt(0)"
               : "+v"(aa0), "+v"(aa1), "+v"(aa2), "+v"(aa3),
                 "+v"(w0), "+v"(w1), "+v"(w2), "+v"(w3));
  f32x4 h0 = {0.f,0.f,0.f,0.f}, h1 = h0, h2 = h0, h3 = h0;
  float bias = dtb[d];
  float dts = 0.f;
  int row = b * 2048 + c * 32;
  const unsigned short* Up = U + (long)row * 512 + d;
  _Float16* DTp = DTH + (long)row * 512 + d;
  for (int tt = 0; tt < 32; tt++, row++, Up += 512, DTp += 512) {
    // XD row is wave-uniform: force scalar loads
    int off = __builtin_amdgcn_readfirstlane(row * 48);
    const f32x4* xs = (const f32x4*)(XD + off);
    f32x4 x0 = xs[0], x1 = xs[1], x2 = xs[2], x3 = xs[3];   // dt_in
    f32x4 B0 = xs[4], B1 = xs[5], B2 = xs[6], B3 = xs[7];   // B
    f32x4 pp = x0 * w0 + x1 * w1 + x2 * w2 + x3 * w3;
    float s = bias + pp.x + pp.y + pp.z + pp.w;
    float e = __expf(-fabsf(s));
    float dt = fmaxf(s, 0.f) + __logf(1.f + e);   // softplus
    if (DTM) *DTp = (_Float16)dt;
    float du = dt * b2f(*Up);
    h0 = exp2v(dt * aa0) * h0 + du * B0;
    h1 = exp2v(dt * aa1) * h1 + du * B1;
    h2 = exp2v(dt * aa2) * h2 + du * B2;
    h3 = exp2v(dt * aa3) * h3 + du * B3;
    dts += dt;
  }
  f32x4* hp = (f32x4*)(HCH + (long)gid * 16);
  hp[0] = h0; hp[1] = h1; hp[2] = h2; hp[3] = h3;
  DTS[gid] = dts;
}

// ---------------- scan pass 2: prefix over chunks (h_end -> h_start) -------
// unroll-4: batches the 4 loads + 4 exps ahead of the serial fma chain
// (p2 is latency-bound at ~2 waves/SIMD). Kept from r12.
__global__ __launch_bounds__(256) void scan_p2(
    float* __restrict__ HCH, const float* __restrict__ DTS,
    const float* __restrict__ AA) {
  int gid = blockIdx.x * 256 + threadIdx.x;   // b*8192 + d*16 + n
  int n = gid & 15;
  int d = (gid >> 4) & 511;
  int b = gid >> 13;
  float aa = AA[d * 16 + n];
  float hrun = 0.f;
  for (int c4 = 0; c4 < 64; c4 += 4) {
    float he0, he1, he2, he3, P0, P1, P2, P3;
    long i0, i1, i2, i3;
    {
      long base0 = ((long)b * 64 + c4 + 0) * 512 + d;
      long base1 = ((long)b * 64 + c4 + 1) * 512 + d;
      long base2 = ((long)b * 64 + c4 + 2) * 512 + d;
      long base3 = ((long)b * 64 + c4 + 3) * 512 + d;
      i0 = base0 * 16 + n; i1 = base1 * 16 + n;
      i2 = base2 * 16 + n; i3 = base3 * 16 + n;
      he0 = HCH[i0]; he1 = HCH[i1]; he2 = HCH[i2]; he3 = HCH[i3];
      P0 = ex2(DTS[base0] * aa); P1 = ex2(DTS[base1] * aa);
      P2 = ex2(DTS[base2] * aa); P3 = ex2(DTS[base3] * aa);
    }
    HCH[i0] = hrun; hrun = fmaf(P0, hrun, he0);
    HCH[i1] = hrun; hrun = fmaf(P1, hrun, he1);
    HCH[i2] = hrun; hrun = fmaf(P2, hrun, he2);
    HCH[i3] = hrun; hrun = fmaf(P3, hrun, he3);
  }
}

// ---------------- scan pass 3: replay with h_start, fused gate -------------
// Y may alias U (same-thread same-element read-before-write)
// DTM: load dt (fp16, written by p1). Single-chunk form (see scan_p1).
template<int DTM>
__global__ __launch_bounds__(256, 4) void scan_p3(
    const unsigned short* __restrict__ U, const unsigned short* __restrict__ Z,
    const float* __restrict__ XD, const float* __restrict__ AA,
    const float* __restrict__ dtw, const float* __restrict__ dtb,
    const float* __restrict__ HCH, const float* __restrict__ skD,
    unsigned short* __restrict__ Y, const _Float16* __restrict__ DTH) {
  int gid = blockIdx.x * 256 + threadIdx.x;
  int d = gid & 511;
  int bc = gid >> 9;
  int c = bc & 63, b = bc >> 6;
  f32x4 aa0 = ld4(AA + d * 16),      aa1 = ld4(AA + d * 16 + 4),
        aa2 = ld4(AA + d * 16 + 8),  aa3 = ld4(AA + d * 16 + 12);
  f32x4 w0, w1, w2, w3;
  if (!DTM) {
    w0 = ld4(dtw + d * 16);     w1 = ld4(dtw + d * 16 + 4);
    w2 = ld4(dtw + d * 16 + 8); w3 = ld4(dtw + d * 16 + 12);
    asm volatile("s_waitcnt vmcnt(0)"
                 : "+v"(aa0), "+v"(aa1), "+v"(aa2), "+v"(aa3),
                   "+v"(w0), "+v"(w1), "+v"(w2), "+v"(w3));
  } else {
    asm volatile("s_waitcnt vmcnt(0)"
                 : "+v"(aa0), "+v"(aa1), "+v"(aa2), "+v"(aa3));
  }
  const f32x4* hp = (const f32x4*)(HCH + (long)gid * 16);
  f32x4 h0 = hp[0], h1 = hp[1], h2 = hp[2], h3 = hp[3];
  float bias = DTM ? 0.f : dtb[d];
  float sD = skD[d];
  int row = b * 2048 + c * 32;
  const unsigned short* Up = U + (long)row * 512 + d;
  const unsigned short* Zp = Z + (long)row * 512 + d;
  unsigned short* Yp = Y + (long)row * 512 + d;
  const _Float16* DTp = DTH + (long)row * 512 + d;
  for (int tt = 0; tt < 32; tt++, row++, Up += 512, Zp += 512, Yp += 512, DTp += 512) {
    int off = __builtin_amdgcn_readfirstlane(row * 48);
    const f32x4* xs = (const f32x4*)(XD + off);
    f32x4 B0 = xs[4], B1 = xs[5], B2 = xs[6], B3 = xs[7];   // B
    f32x4 C0 = xs[8], C1 = xs[9], C2 = xs[10], C3 = xs[11]; // C
    float dt;
    if (DTM) {
      dt = (float)*DTp;
    } else {
      f32x4 x0 = xs[0], x1 = xs[1], x2 = xs[2], x3 = xs[3]; // dt_in
      f32x4 pp = x0 * w0 + x1 * w1 + x2 * w2 + x3 * w3;
      float s = bias + pp.x + pp.y + pp.z + pp.w;
      float e = __expf(-fabsf(s));
      dt = fmaxf(s, 0.f) + __logf(1.f + e);
    }
    float u = b2f(*Up);
    float du = dt * u;
    h0 = exp2v(dt * aa0) * h0 + du * B0;
    h1 = exp2v(dt * aa1) * h1 + du * B1;
    h2 = exp2v(dt * aa2) * h2 + du * B2;
    h3 = exp2v(dt * aa3) * h3 + du * B3;
    f32x4 yv = h0 * C0 + h1 * C1 + h2 * C2 + h3 * C3;
    float y = yv.x + yv.y + yv.z + yv.w + u * sD;
    float z = b2f(*Zp);
    float sg = z / (1.f + __expf(-z));      // silu(z)
    *Yp = f2b(y * sg);
  }
}

extern "C" void kernel_launch(void* const* d_in, const int* in_sizes, int n_in,
                              void* d_out, int out_size, void* d_ws, size_t ws_size,
                              hipStream_t stream) {
  const float* x        = (const float*)d_in[0];
  const int*   mask     = (const int*)d_in[1];
  const float* ln_w     = (const float*)d_in[2];
  const float* ln_b     = (const float*)d_in[3];
  const float* in_proj  = (const float*)d_in[4];
  const float* conv_w   = (const float*)d_in[5];
  const float* conv_b   = (const float*)d_in[6];
  const float* x_proj   = (const float*)d_in[7];
  const float* dt_w     = (const float*)d_in[8];
  const float* dt_b     = (const float*)d_in[9];
  const float* A_log    = (const float*)d_in[10];
  const float* skip_D   = (const float*)d_in[11];
  const float* out_proj = (const float*)d_in[12];
  float* X = (float*)d_out;

  // ---- workspace layout (~114 MB base, +33.5 MB DT when ws allows) ----
  char* p = (char*)d_ws;
  auto alloc = [&](size_t n) { char* r = p; p += (n + 255) & ~(size_t)255; return r; };
  unsigned short* WBin  = (unsigned short*)alloc((size_t)2 * 1024 * 256 * 2);  // 1 MB
  unsigned short* WBx   = (unsigned short*)alloc((size_t)2 * 48 * 512 * 2);
  unsigned short* WBout = (unsigned short*)alloc((size_t)2 * 256 * 512 * 2);
  float*          AA    = (float*)alloc((size_t)2 * 512 * 16 * 4);
  char* R_XN   = alloc((size_t)RC * 256 * 2);        // 16 MB: XN, then XD+DTS
  char* R_UPRE = alloc((size_t)RC * 512 * 2);        // 32 MB: Upre, then HCH
  char* R_Z    = alloc((size_t)RC * 512 * 2);        // 32 MB: Z
  char* R_U    = alloc((size_t)RC * 512 * 2);        // 32 MB: U (=Y in-place)
  char* R_DT   = alloc((size_t)RC * 512 * 2);        // 32 MB: dt fp16 (optional)

  unsigned short* XN   = (unsigned short*)R_XN;
  float*          XD   = (float*)R_XN;                         // after in_proj
  float*          DTS  = (float*)(R_XN + 8388608);             // 2 MB @ +8 MB
  unsigned short* Upre = (unsigned short*)R_UPRE;
  float*          HCH  = (float*)R_UPRE;                       // after conv
  unsigned short* Z    = (unsigned short*)R_Z;
  unsigned short* U    = (unsigned short*)R_U;
  _Float16*       DTH  = (_Float16*)R_DT;

  // dt-persist path needs the whole layout incl. R_DT to fit the workspace
  const bool use_dt = ws_size >= (size_t)((char*)p - (char*)d_ws);

  prep_weights<<<3328, 256, 0, stream>>>(in_proj, x_proj, out_proj, A_log,
                                         WBin, WBx, WBout, AA);

  for (int ch = 0; ch < 2; ch++) {
    const long row0 = (long)ch * RC;
    float* Xc = X + row0 * 256;
    const int* maskc = mask + row0;
    for (int i = 0; i < 2; i++) {
      if (i == 0) {
        // layer 0: mask + write masked residual X + LN, one pass
        ln_mask_fwd<<<RC / 4, 256, 0, stream>>>(x + row0 * 256, maskc,
            ln_w, ln_b, Xc, XN);
      } else {
        ln_fwd<<<RC / 4, 256, 0, stream>>>(Xc, ln_w + i * 256, ln_b + i * 256, XN);
      }
      gemm128<<<dim3(RC / 128, 8), 256, 0, stream>>>(XN, WBin + i * 262144,
          Upre, Z, 1024, 256);
      conv_silu<<<RC / 4, 256, 0, stream>>>(Upre, conv_w + i * 2048,
          conv_b + i * 512, U);
      gemm_n48<<<RC / 128, 256, 0, stream>>>(U, WBx + i * 24576, XD, 512);
      if (use_dt) {
        scan_p1<1><<<BCH * 128, 256, 0, stream>>>(U, XD, AA + i * 8192,
            dt_w + i * 8192, dt_b + i * 512, HCH, DTS, DTH);
      } else {
        scan_p1<0><<<BCH * 128, 256, 0, stream>>>(U, XD, AA + i * 8192,
            dt_w + i * 8192, dt_b + i * 512, HCH, DTS, DTH);
      }
      scan_p2<<<BCH * 32, 256, 0, stream>>>(HCH, DTS, AA + i * 8192);
      if (use_dt) {
        scan_p3<1><<<BCH * 128, 256, 0, stream>>>(U, Z, XD, AA + i * 8192,
            dt_w + i * 8192, dt_b + i * 512, HCH, skip_D + i * 512, U, DTH);
      } else {
        scan_p3<0><<<BCH * 128, 256, 0, stream>>>(U, Z, XD, AA + i * 8192,
            dt_w + i * 8192, dt_b + i * 512, HCH, skip_D + i * 512, U, DTH);
      }
      gemm64<<<dim3(RC / 64, 2), 256, 0, stream>>>(U, WBout + i * 131072,
          Xc, Xc, maskc, 256, 512);
    }
  }
}